// Round 2
// baseline (190.992 us; speedup 1.0000x reference)
//
#include <hip/hip_runtime.h>
#include <hip/hip_bf16.h>
#include <math.h>

typedef __bf16 bf16_8 __attribute__((ext_vector_type(8)));
typedef float f32x4 __attribute__((ext_vector_type(4)));

#define D_ 256
#define S_ 128
#define E_ 512
#define MPE_ 4096
#define B_ 2
#define N_ 4096
#define M_TOT (B_*N_)   // 8192

__device__ __forceinline__ ushort f2b(float f) {
  union { float f; uint u; } x; x.f = f;
  uint r = (x.u + 0x7FFFu + ((x.u >> 16) & 1u)) >> 16;
  return (ushort)r;
}
__device__ __forceinline__ float b2f(ushort b) {
  union { uint u; float f; } x; x.u = ((uint)b) << 16;
  return x.f;
}

__device__ __forceinline__ void gl_lds16(const void* g, void* l) {
  __builtin_amdgcn_global_load_lds(
      (const __attribute__((address_space(1))) void*)g,
      (__attribute__((address_space(3))) void*)l, 16, 0, 0);
}

// ---------------- LayerNorm: one wave per row ----------------
__global__ __launch_bounds__(256) void ln_kernel(const float* __restrict__ q,
    const float* __restrict__ w, const float* __restrict__ b,
    ushort* __restrict__ x) {
  int wid = threadIdx.x >> 6, lane = threadIdx.x & 63;
  int row = blockIdx.x * 4 + wid;
  const float* qr = q + (size_t)row * D_;
  float4 v = *(const float4*)(qr + lane * 4);
  float s  = v.x + v.y + v.z + v.w;
  float ss = v.x*v.x + v.y*v.y + v.z*v.z + v.w*v.w;
  #pragma unroll
  for (int off = 32; off; off >>= 1) {
    s  += __shfl_xor(s, off);
    ss += __shfl_xor(ss, off);
  }
  float mu   = s * (1.0f / 256.0f);
  float var  = ss * (1.0f / 256.0f) - mu * mu;
  float rstd = rsqrtf(var + 1e-5f);
  ushort4 o;
  float vv[4] = {v.x, v.y, v.z, v.w};
  ushort ot[4];
  #pragma unroll
  for (int j = 0; j < 4; ++j) {
    int c = lane * 4 + j;
    ot[j] = f2b((vv[j] - mu) * rstd * w[c] + b[c]);
  }
  o.x = ot[0]; o.y = ot[1]; o.z = ot[2]; o.w = ot[3];
  *(ushort4*)(x + (size_t)row * D_ + lane * 4) = o;
}

// ---------------- weight transpose + cast ----------------
__global__ void wt_kernel(const float* __restrict__ in, ushort* __restrict__ out,
                          int R, int C) {
  int o = blockIdx.x * 256 + threadIdx.x;
  if (o >= R * C) return;
  int c = o / R, r = o - c * R;
  out[o] = f2b(in[r * C + c]);
}

// ---------------- GEMM: A[M][K] bf16, Bt[N][K] bf16, tile 128x64, BK=64 ----------------
template<int EPI>
__global__ __launch_bounds__(256) void gemm_kernel(
    const ushort* __restrict__ A, const ushort* __restrict__ Bt,
    const float* __restrict__ bias, void* __restrict__ out,
    int M, int N, int K) {
  __shared__ alignas(16) ushort As[128 * 64];
  __shared__ alignas(16) ushort Bs[64 * 64];
  int tid = threadIdx.x;
  int lane = tid & 63, wid = tid >> 6;
  int m0 = blockIdx.x * 128, n0 = blockIdx.y * 64;
  int r16 = lane & 15, kq = lane >> 4;
  f32x4 acc[2][4] = {};
  for (int k0 = 0; k0 < K; k0 += 64) {
    __syncthreads();
    #pragma unroll
    for (int t = 0; t < 4; ++t) {
      int cid = tid + t * 256;
      int row = cid >> 3, c = cid & 7;
      uint4 d = *(const uint4*)(A + ((size_t)(m0 + row) * K + k0 + c * 8));
      *(uint4*)&As[row * 64 + ((c ^ (row & 7)) * 8)] = d;
    }
    #pragma unroll
    for (int t = 0; t < 2; ++t) {
      int cid = tid + t * 256;
      int row = cid >> 3, c = cid & 7;
      uint4 d = *(const uint4*)(Bt + ((size_t)(n0 + row) * K + k0 + c * 8));
      *(uint4*)&Bs[row * 64 + ((c ^ (row & 7)) * 8)] = d;
    }
    __syncthreads();
    #pragma unroll
    for (int ks = 0; ks < 2; ++ks) {
      bf16_8 af[2], bfr[4];
      int c = ks * 4 + kq;
      #pragma unroll
      for (int fm = 0; fm < 2; ++fm) {
        int r = wid * 32 + fm * 16 + r16;
        af[fm] = *(const bf16_8*)&As[r * 64 + ((c ^ (r & 7)) * 8)];
      }
      #pragma unroll
      for (int fn = 0; fn < 4; ++fn) {
        int r = fn * 16 + r16;
        bfr[fn] = *(const bf16_8*)&Bs[r * 64 + ((c ^ (r & 7)) * 8)];
      }
      #pragma unroll
      for (int fm = 0; fm < 2; ++fm)
        #pragma unroll
        for (int fn = 0; fn < 4; ++fn)
          acc[fm][fn] = __builtin_amdgcn_mfma_f32_16x16x32_bf16(af[fm], bfr[fn], acc[fm][fn], 0, 0, 0);
    }
  }
  #pragma unroll
  for (int fm = 0; fm < 2; ++fm)
    #pragma unroll
    for (int fn = 0; fn < 4; ++fn)
      #pragma unroll
      for (int reg = 0; reg < 4; ++reg) {
        int ml = wid * 32 + fm * 16 + kq * 4 + reg;
        int nl = fn * 16 + r16;
        size_t gm = m0 + ml, gn = n0 + nl;
        float val = acc[fm][fn][reg] + bias[gn];
        if (EPI == 0) {
          float y = val / (1.0f + expf(-val));
          ((ushort*)out)[gm * N + gn] = f2b(y);
        } else if (EPI == 2) {
          float y = val / (1.0f + expf(-val));
          ((ushort*)out)[gn * (size_t)M_TOT + gm] = f2b(y);
        } else {
          ((float*)out)[gm * N + gn] = val;
        }
      }
}

// ---------------- RoPE ----------------
__global__ __launch_bounds__(256) void rope_kernel(const ushort* __restrict__ base,
    const float* __restrict__ qw, const float* __restrict__ qb,
    const float* __restrict__ kw, const float* __restrict__ kb,
    ushort* __restrict__ Q, ushort* __restrict__ Kk) {
  int g = blockIdx.x * 256 + threadIdx.x;
  int row = g >> 6, i = g & 63;
  int n = row & (N_ - 1);
  float invf = powf(10000.0f, -(float)i * (1.0f / 64.0f));
  float sv, cv;
  sincosf((float)n * invf, &sv, &cv);
  float b1 = b2f(base[row * S_ + i]), b2 = b2f(base[row * S_ + 64 + i]);
  float x1q = b1 * qw[i] + qb[i], x2q = b2 * qw[64 + i] + qb[64 + i];
  Q[row * S_ + i]      = f2b(x1q * cv - x2q * sv);
  Q[row * S_ + 64 + i] = f2b(x2q * cv + x1q * sv);
  float x1k = b1 * kw[i] + kb[i], x2k = b2 * kw[64 + i] + kb[64 + i];
  Kk[row * S_ + i]      = f2b(x1k * cv - x2k * sv);
  Kk[row * S_ + 64 + i] = f2b(x2k * cv + x1k * sv);
}

// ---------------- fused attention: 2-phase async pipeline ----------------
// grid (32 m-tiles of 128, 4 e-chunks of 128, 2 b), block 256 = 4 waves,
// each wave owns 32 m-rows x 128 e. Q in registers. K/V double-buffered LDS
// staged via global_load_lds with pre-swizzled global source. One barrier/tile.
__global__ __launch_bounds__(256, 1) void attn_kernel(
    const ushort* __restrict__ Q, const ushort* __restrict__ Kd,
    const ushort* __restrict__ VT, const ushort* __restrict__ U,
    const float* __restrict__ w_rel, ushort* __restrict__ KVU) {
  __shared__ alignas(16) ushort Ks[2][64 * 128];   // 32 KB
  __shared__ alignas(16) ushort Vs[2][128 * 64];   // 32 KB
  __shared__ alignas(16) ushort Ps[4][32 * 64];    // 16 KB
  __shared__ float WrL[2][192];                    // 1.5 KB
  int tid = threadIdx.x, lane = tid & 63, wid = tid >> 6;
  int b = blockIdx.z, m0 = blockIdx.x * 128, e0 = blockIdx.y * 128;
  int r16 = lane & 15, kq = lane >> 4;
  const float inv_mpe = 1.0f / (float)MPE_;

  // Q fragments in registers: 32 rows x 128 k per wave
  bf16_8 qf[2][4];
  #pragma unroll
  for (int fm = 0; fm < 2; ++fm)
    #pragma unroll
    for (int ks = 0; ks < 4; ++ks)
      qf[fm][ks] = *(const bf16_8*)(Q +
          ((size_t)(b * N_ + m0 + wid * 32 + fm * 16 + r16) * S_ + ks * 32 + kq * 8));

  auto stage = [&](int bi, int t) {
    int n0s = t * 64;
    #pragma unroll
    for (int tt = 0; tt < 4; ++tt) {           // K tile: 64 rows x 16 chunks
      int p = tt * 256 + wid * 64 + lane;
      int row = p >> 4, sc = p & 15;
      int cc = sc ^ (row & 7);                 // inverse-swizzled source
      gl_lds16(Kd + ((size_t)(b * N_ + n0s + row) * S_ + cc * 8),
               &Ks[bi][(tt * 256 + wid * 64) * 8]);
    }
    #pragma unroll
    for (int tt = 0; tt < 4; ++tt) {           // V^T tile: 128 e-rows x 8 chunks
      int p = tt * 256 + wid * 64 + lane;
      int er = p >> 3, sc = p & 7;
      int nc = sc ^ (er & 7);
      gl_lds16(VT + ((size_t)(e0 + er) * M_TOT + b * N_ + n0s + nc * 8),
               &Vs[bi][(tt * 256 + wid * 64) * 8]);
    }
    if (tid < 192) {
      int idx = 3968 + t * 64 - m0 + tid;
      if (idx > 8190) idx = 8190;
      WrL[bi][tid] = w_rel[idx];
    }
  };

  f32x4 pv[2][8] = {};
  stage(0, 0);
  asm volatile("s_waitcnt vmcnt(0) lgkmcnt(0)" ::: "memory");
  __builtin_amdgcn_s_barrier();

  for (int t = 0; t < 64; ++t) {
    int cur = t & 1;
    if (t + 1 < 64) stage(cur ^ 1, t + 1);
    const ushort* ksb = Ks[cur];
    const ushort* vsb = Vs[cur];
    // ---- QK^T: S[32m x 64n] per wave ----
    f32x4 sacc[2][4] = {};
    #pragma unroll
    for (int ks = 0; ks < 4; ++ks) {
      int cc = ks * 4 + kq;
      #pragma unroll
      for (int fn = 0; fn < 4; ++fn) {
        int r = fn * 16 + r16;
        bf16_8 kf = *(const bf16_8*)&ksb[r * 128 + ((cc ^ (r & 7)) * 8)];
        #pragma unroll
        for (int fm = 0; fm < 2; ++fm)
          sacc[fm][fn] = __builtin_amdgcn_mfma_f32_16x16x32_bf16(qf[fm][ks], kf, sacc[fm][fn], 0, 0, 0);
      }
    }
    // ---- P transform -> private Ps (same-wave, no barrier) ----
    char* psb = (char*)&Ps[wid][0];
    #pragma unroll
    for (int fm = 0; fm < 2; ++fm)
      #pragma unroll
      for (int fn = 0; fn < 4; ++fn)
        #pragma unroll
        for (int reg = 0; reg < 4; ++reg) {
          int ml = fm * 16 + kq * 4 + reg;     // 0..31 (within wave's rows)
          int nl = fn * 16 + r16;              // 0..63
          float tv = sacc[fm][fn][reg] * inv_mpe + WrL[cur][127 + nl - wid * 32 - ml];
          tv = fmaxf(tv, 0.0f);
          *(ushort*)(psb + ((ml * 128 + nl * 2) ^ ((ml & 7) << 4))) = f2b(tv * tv);
        }
    // ---- PV: acc += P[32m x 64n] @ V[64n x 128e] ----
    #pragma unroll
    for (int ks = 0; ks < 2; ++ks) {
      bf16_8 pa[2];
      #pragma unroll
      for (int fm = 0; fm < 2; ++fm) {
        int r = fm * 16 + r16;
        pa[fm] = *(const bf16_8*)(psb + ((r * 128 + ks * 64 + kq * 16) ^ ((r & 7) << 4)));
      }
      #pragma unroll
      for (int fe = 0; fe < 8; ++fe) {
        int r = fe * 16 + r16;
        bf16_8 vf = *(const bf16_8*)&vsb[r * 64 + (((ks * 4 + kq) ^ (r & 7)) * 8)];
        #pragma unroll
        for (int fm = 0; fm < 2; ++fm)
          pv[fm][fe] = __builtin_amdgcn_mfma_f32_16x16x32_bf16(pa[fm], vf, pv[fm][fe], 0, 0, 0);
      }
    }
    asm volatile("s_waitcnt vmcnt(0) lgkmcnt(0)" ::: "memory");
    __builtin_amdgcn_s_barrier();
  }

  // ---- epilogue: KVU = bf16(u * pv) ----
  #pragma unroll
  for (int fm = 0; fm < 2; ++fm)
    #pragma unroll
    for (int fe = 0; fe < 8; ++fe)
      #pragma unroll
      for (int reg = 0; reg < 4; ++reg) {
        int ml = fm * 16 + kq * 4 + reg;
        size_t grow = (size_t)b * N_ + m0 + wid * 32 + ml;
        size_t ge = e0 + fe * 16 + r16;
        float uu = b2f(U[grow * E_ + ge]);
        KVU[grow * E_ + ge] = f2b(uu * pv[fm][fe][reg]);
      }
}

extern "C" void kernel_launch(void* const* d_in, const int* in_sizes, int n_in,
                              void* d_out, int out_size, void* d_ws, size_t ws_size,
                              hipStream_t stream) {
  const float* query = (const float*)d_in[0];
  const float* ln_w  = (const float*)d_in[1];
  const float* ln_b  = (const float*)d_in[2];
  const float* Wu    = (const float*)d_in[3];
  const float* bu    = (const float*)d_in[4];
  const float* Wv    = (const float*)d_in[5];
  const float* bv    = (const float*)d_in[6];
  const float* Wbase = (const float*)d_in[7];
  const float* bbase = (const float*)d_in[8];
  const float* q_w   = (const float*)d_in[9];
  const float* q_b   = (const float*)d_in[10];
  const float* k_w   = (const float*)d_in[11];
  const float* k_b   = (const float*)d_in[12];
  const float* w_rel = (const float*)d_in[13];
  const float* Wo    = (const float*)d_in[14];
  const float* bo    = (const float*)d_in[15];
  float* out = (float*)d_out;

  char* ws = (char*)d_ws;
  ushort* X    = (ushort*)(ws);                     // 8192*256  (4 MB)
  ushort* U    = (ushort*)(ws + (4u  << 20));       // 8192*512  (8 MB)
  ushort* VT   = (ushort*)(ws + (12u << 20));       // 512*8192  (8 MB)
  ushort* BASE = (ushort*)(ws + (20u << 20));       // 8192*128  (2 MB)
  ushort* Qb   = (ushort*)(ws + (22u << 20));       // 2 MB
  ushort* Kb   = (ushort*)(ws + (24u << 20));       // 2 MB
  ushort* KVU  = (ushort*)(ws + (26u << 20));       // 8 MB
  ushort* WUT  = (ushort*)(ws + (34u << 20));
  ushort* WVT  = (ushort*)(ws + (34u << 20) + 512*256*2);
  ushort* WBT  = (ushort*)(ws + (34u << 20) + 2*512*256*2);
  ushort* WOT  = (ushort*)(ws + (34u << 20) + 2*512*256*2 + 128*256*2);

  ln_kernel<<<2048, 256, 0, stream>>>(query, ln_w, ln_b, X);
  wt_kernel<<<(512*256 + 255) / 256, 256, 0, stream>>>(Wu, WUT, 256, 512);
  wt_kernel<<<(512*256 + 255) / 256, 256, 0, stream>>>(Wv, WVT, 256, 512);
  wt_kernel<<<(128*256 + 255) / 256, 256, 0, stream>>>(Wbase, WBT, 256, 128);
  wt_kernel<<<(512*256 + 255) / 256, 256, 0, stream>>>(Wo, WOT, 512, 256);
  gemm_kernel<0><<<dim3(64, 8), 256, 0, stream>>>(X, WUT, bu, U, 8192, 512, 256);
  gemm_kernel<2><<<dim3(64, 8), 256, 0, stream>>>(X, WVT, bv, VT, 8192, 512, 256);
  gemm_kernel<0><<<dim3(64, 2), 256, 0, stream>>>(X, WBT, bbase, BASE, 8192, 128, 256);
  rope_kernel<<<2048, 256, 0, stream>>>(BASE, q_w, q_b, k_w, k_b, Qb, Kb);
  attn_kernel<<<dim3(32, 4, 2), 256, 0, stream>>>(Qb, Kb, VT, U, w_rel, KVU);
  gemm_kernel<1><<<dim3(64, 4), 256, 0, stream>>>(KVU, WOT, bo, out, 8192, 256, 512);
}

// Round 3
// 157.785 us; speedup vs baseline: 1.2105x; 1.2105x over previous
//
#include <hip/hip_runtime.h>
#include <hip/hip_bf16.h>
#include <math.h>

typedef __bf16 bf16_8 __attribute__((ext_vector_type(8)));
typedef float f32x4 __attribute__((ext_vector_type(4)));

#define D_ 256
#define S_ 128
#define E_ 512
#define MPE_ 4096
#define B_ 2
#define N_ 4096
#define M_TOT (B_*N_)   // 8192

__device__ __forceinline__ ushort f2b(float f) {
  union { float f; uint u; } x; x.f = f;
  uint r = (x.u + 0x7FFFu + ((x.u >> 16) & 1u)) >> 16;
  return (ushort)r;
}
__device__ __forceinline__ float b2f(ushort b) {
  union { uint u; float f; } x; x.u = ((uint)b) << 16;
  return x.f;
}

__device__ __forceinline__ void gl_lds16(const void* g, void* l) {
  __builtin_amdgcn_global_load_lds(
      (const __attribute__((address_space(1))) void*)g,
      (__attribute__((address_space(3))) void*)l, 16, 0, 0);
}

// ---------------- LayerNorm: one wave per row ----------------
__global__ __launch_bounds__(256) void ln_kernel(const float* __restrict__ q,
    const float* __restrict__ w, const float* __restrict__ b,
    ushort* __restrict__ x) {
  int wid = threadIdx.x >> 6, lane = threadIdx.x & 63;
  int row = blockIdx.x * 4 + wid;
  const float* qr = q + (size_t)row * D_;
  float4 v = *(const float4*)(qr + lane * 4);
  float s  = v.x + v.y + v.z + v.w;
  float ss = v.x*v.x + v.y*v.y + v.z*v.z + v.w*v.w;
  #pragma unroll
  for (int off = 32; off; off >>= 1) {
    s  += __shfl_xor(s, off);
    ss += __shfl_xor(ss, off);
  }
  float mu   = s * (1.0f / 256.0f);
  float var  = ss * (1.0f / 256.0f) - mu * mu;
  float rstd = rsqrtf(var + 1e-5f);
  ushort4 o;
  float vv[4] = {v.x, v.y, v.z, v.w};
  ushort ot[4];
  #pragma unroll
  for (int j = 0; j < 4; ++j) {
    int c = lane * 4 + j;
    ot[j] = f2b((vv[j] - mu) * rstd * w[c] + b[c]);
  }
  o.x = ot[0]; o.y = ot[1]; o.z = ot[2]; o.w = ot[3];
  *(ushort4*)(x + (size_t)row * D_ + lane * 4) = o;
}

// ---------------- weight transpose + cast ----------------
__global__ void wt_kernel(const float* __restrict__ in, ushort* __restrict__ out,
                          int R, int C) {
  int o = blockIdx.x * 256 + threadIdx.x;
  if (o >= R * C) return;
  int c = o / R, r = o - c * R;
  out[o] = f2b(in[r * C + c]);
}

// ---------------- GEMM: A[M][K] bf16, Bt[N][K] bf16, tile 128x64, BK=64 ----------------
template<int EPI>
__global__ __launch_bounds__(256) void gemm_kernel(
    const ushort* __restrict__ A, const ushort* __restrict__ Bt,
    const float* __restrict__ bias, void* __restrict__ out,
    int M, int N, int K) {
  __shared__ alignas(16) ushort As[128 * 64];
  __shared__ alignas(16) ushort Bs[64 * 64];
  int tid = threadIdx.x;
  int lane = tid & 63, wid = tid >> 6;
  int m0 = blockIdx.x * 128, n0 = blockIdx.y * 64;
  int r16 = lane & 15, kq = lane >> 4;
  f32x4 acc[2][4] = {};
  for (int k0 = 0; k0 < K; k0 += 64) {
    __syncthreads();
    #pragma unroll
    for (int t = 0; t < 4; ++t) {
      int cid = tid + t * 256;
      int row = cid >> 3, c = cid & 7;
      uint4 d = *(const uint4*)(A + ((size_t)(m0 + row) * K + k0 + c * 8));
      *(uint4*)&As[row * 64 + ((c ^ (row & 7)) * 8)] = d;
    }
    #pragma unroll
    for (int t = 0; t < 2; ++t) {
      int cid = tid + t * 256;
      int row = cid >> 3, c = cid & 7;
      uint4 d = *(const uint4*)(Bt + ((size_t)(n0 + row) * K + k0 + c * 8));
      *(uint4*)&Bs[row * 64 + ((c ^ (row & 7)) * 8)] = d;
    }
    __syncthreads();
    #pragma unroll
    for (int ks = 0; ks < 2; ++ks) {
      bf16_8 af[2], bfr[4];
      int c = ks * 4 + kq;
      #pragma unroll
      for (int fm = 0; fm < 2; ++fm) {
        int r = wid * 32 + fm * 16 + r16;
        af[fm] = *(const bf16_8*)&As[r * 64 + ((c ^ (r & 7)) * 8)];
      }
      #pragma unroll
      for (int fn = 0; fn < 4; ++fn) {
        int r = fn * 16 + r16;
        bfr[fn] = *(const bf16_8*)&Bs[r * 64 + ((c ^ (r & 7)) * 8)];
      }
      #pragma unroll
      for (int fm = 0; fm < 2; ++fm)
        #pragma unroll
        for (int fn = 0; fn < 4; ++fn)
          acc[fm][fn] = __builtin_amdgcn_mfma_f32_16x16x32_bf16(af[fm], bfr[fn], acc[fm][fn], 0, 0, 0);
    }
  }
  #pragma unroll
  for (int fm = 0; fm < 2; ++fm)
    #pragma unroll
    for (int fn = 0; fn < 4; ++fn)
      #pragma unroll
      for (int reg = 0; reg < 4; ++reg) {
        int ml = wid * 32 + fm * 16 + kq * 4 + reg;
        int nl = fn * 16 + r16;
        size_t gm = m0 + ml, gn = n0 + nl;
        float val = acc[fm][fn][reg] + bias[gn];
        if (EPI == 0) {
          float y = val / (1.0f + expf(-val));
          ((ushort*)out)[gm * N + gn] = f2b(y);
        } else if (EPI == 2) {
          float y = val / (1.0f + expf(-val));
          ((ushort*)out)[gn * (size_t)M_TOT + gm] = f2b(y);
        } else {
          ((float*)out)[gm * N + gn] = val;
        }
      }
}

// ---------------- RoPE (outputs pre-scaled by 1/64 so q.k carries 1/MPE) ----------------
__global__ __launch_bounds__(256) void rope_kernel(const ushort* __restrict__ base,
    const float* __restrict__ qw, const float* __restrict__ qb,
    const float* __restrict__ kw, const float* __restrict__ kb,
    ushort* __restrict__ Q, ushort* __restrict__ Kk) {
  int g = blockIdx.x * 256 + threadIdx.x;
  int row = g >> 6, i = g & 63;
  int n = row & (N_ - 1);
  float invf = powf(10000.0f, -(float)i * (1.0f / 64.0f));
  float sv, cv;
  sincosf((float)n * invf, &sv, &cv);
  const float sc = 0.015625f;   // 1/64; (1/64)^2 = 1/4096 = 1/MPE
  float b1 = b2f(base[row * S_ + i]), b2 = b2f(base[row * S_ + 64 + i]);
  float x1q = b1 * qw[i] + qb[i], x2q = b2 * qw[64 + i] + qb[64 + i];
  Q[row * S_ + i]      = f2b((x1q * cv - x2q * sv) * sc);
  Q[row * S_ + 64 + i] = f2b((x2q * cv + x1q * sv) * sc);
  float x1k = b1 * kw[i] + kb[i], x2k = b2 * kw[64 + i] + kb[64 + i];
  Kk[row * S_ + i]      = f2b((x1k * cv - x2k * sv) * sc);
  Kk[row * S_ + 64 + i] = f2b((x2k * cv + x1k * sv) * sc);
}

// ---------------- fused attention ----------------
// grid (64 m-tiles of 64, 4 e-chunks of 128, 2 b) = 512 blocks, 256 thr (4 waves).
// LDS 73KB -> 2 blocks/CU (2 waves/SIMD). Q in regs. K/V double-buffered via
// global_load_lds (pre-swizzled source). Waves: QK as 2m x 2n, PV as 2m x 2e.
// P shared per 32-row m-group. Mid barrier lgkm-only; end barrier drains vmcnt.
__global__ __launch_bounds__(256, 2) void attn_kernel(
    const ushort* __restrict__ Q, const ushort* __restrict__ Kd,
    const ushort* __restrict__ VT, const ushort* __restrict__ U,
    const float* __restrict__ w_rel, ushort* __restrict__ KVU) {
  __shared__ alignas(16) ushort Ks[2][64 * 128];   // 32 KB
  __shared__ alignas(16) ushort Vs[2][128 * 64];   // 32 KB
  __shared__ alignas(16) ushort Pb[2][32 * 64];    // 8 KB (per m-group)
  __shared__ float WrL[2][128];                    // 1 KB
  const int tid = threadIdx.x, lane = tid & 63, wid = tid >> 6;
  const int b = blockIdx.z, m0 = blockIdx.x * 64, e0 = blockIdx.y * 128;
  const int r16 = lane & 15, kq = lane >> 4;
  const int wm = wid >> 1, wl = wid & 1;

  // Q fragments: wave's 32 m-rows x 128 k
  bf16_8 qf[2][4];
  #pragma unroll
  for (int fm = 0; fm < 2; ++fm)
    #pragma unroll
    for (int ks = 0; ks < 4; ++ks)
      qf[fm][ks] = *(const bf16_8*)(Q +
          ((size_t)(b * N_ + m0 + wm * 32 + fm * 16 + r16) * S_ + ks * 32 + kq * 8));

  auto stage_kv = [&](int bi, int t) {
    int n0s = t * 64;
    #pragma unroll
    for (int tt = 0; tt < 4; ++tt) {           // K tile: 64 rows x 16 chunks
      int p = tt * 256 + wid * 64 + lane;
      int row = p >> 4, sc2 = p & 15;
      int cc = sc2 ^ (row & 7);
      gl_lds16(Kd + ((size_t)(b * N_ + n0s + row) * S_ + cc * 8),
               &Ks[bi][(tt * 256 + wid * 64) * 8]);
    }
    #pragma unroll
    for (int tt = 0; tt < 4; ++tt) {           // V^T tile: 128 e-rows x 8 chunks
      int p = tt * 256 + wid * 64 + lane;
      int er = p >> 3, sc2 = p & 7;
      int nc = sc2 ^ (er & 7);
      gl_lds16(VT + ((size_t)(e0 + er) * M_TOT + b * N_ + n0s + nc * 8),
               &Vs[bi][(tt * 256 + wid * 64) * 8]);
    }
  };

  f32x4 pv[2][4] = {};

  stage_kv(0, 0);
  if (tid < 127) WrL[0][tid] = w_rel[4032 - m0 + tid];
  asm volatile("s_waitcnt vmcnt(0) lgkmcnt(0)" ::: "memory");
  __builtin_amdgcn_s_barrier();

  auto body = [&](int CUR, int t) {
    // T14 split: issue next-iter w_rel load early, ds_write after QK
    float wv = 0.f;
    bool hw = (t < 63) && (tid < 127);
    if (hw) wv = w_rel[4032 + (t + 1) * 64 - m0 + tid];
    if (t < 63) stage_kv(CUR ^ 1, t + 1);
    const ushort* ksb = Ks[CUR];
    // ---- QK: S[32m x 32n] per wave (waves 2m x 2n) ----
    f32x4 sacc[2][2] = {};
    __builtin_amdgcn_s_setprio(1);
    #pragma unroll
    for (int ks = 0; ks < 4; ++ks) {
      bf16_8 kf[2];
      #pragma unroll
      for (int fn = 0; fn < 2; ++fn) {
        int r = wl * 32 + fn * 16 + r16;
        int c = ks * 4 + kq;
        kf[fn] = *(const bf16_8*)&ksb[r * 128 + ((c ^ (r & 7)) * 8)];
      }
      #pragma unroll
      for (int fm = 0; fm < 2; ++fm)
        #pragma unroll
        for (int fn = 0; fn < 2; ++fn)
          sacc[fm][fn] = __builtin_amdgcn_mfma_f32_16x16x32_bf16(qf[fm][ks], kf[fn], sacc[fm][fn], 0, 0, 0);
    }
    __builtin_amdgcn_s_setprio(0);
    if (hw) WrL[CUR ^ 1][tid] = wv;
    // ---- transform -> Pb[wm] (bf16, swizzled) ----
    char* psb = (char*)&Pb[wm][0];
    #pragma unroll
    for (int fm = 0; fm < 2; ++fm)
      #pragma unroll
      for (int fn = 0; fn < 2; ++fn)
        #pragma unroll
        for (int reg = 0; reg < 4; ++reg) {
          int ml = fm * 16 + kq * 4 + reg;          // 0..31 in group
          int nl = wl * 32 + fn * 16 + r16;         // 0..63
          float tv = sacc[fm][fn][reg] + WrL[CUR][63 + nl - wm * 32 - ml];
          tv = fmaxf(tv, 0.0f);
          *(ushort*)(psb + ((ml * 128 + nl * 2) ^ ((ml & 7) << 4))) = f2b(tv * tv);
        }
    asm volatile("s_waitcnt lgkmcnt(0)" ::: "memory");
    __builtin_amdgcn_s_barrier();
    // ---- PV: out[32m x 64e] per wave (waves 2m x 2e), k = 64n ----
    const ushort* vsb = Vs[CUR];
    __builtin_amdgcn_s_setprio(1);
    #pragma unroll
    for (int ks = 0; ks < 2; ++ks) {
      bf16_8 pa[2];
      #pragma unroll
      for (int fm = 0; fm < 2; ++fm) {
        int r = fm * 16 + r16;
        pa[fm] = *(const bf16_8*)(psb + ((r * 128 + ks * 64 + kq * 16) ^ ((r & 7) << 4)));
      }
      #pragma unroll
      for (int fe = 0; fe < 4; ++fe) {
        int rv = wl * 64 + fe * 16 + r16;
        int cv = ks * 4 + kq;
        bf16_8 vf = *(const bf16_8*)&vsb[rv * 64 + ((cv ^ (rv & 7)) * 8)];
        #pragma unroll
        for (int fm = 0; fm < 2; ++fm)
          pv[fm][fe] = __builtin_amdgcn_mfma_f32_16x16x32_bf16(pa[fm], vf, pv[fm][fe], 0, 0, 0);
      }
    }
    __builtin_amdgcn_s_setprio(0);
    asm volatile("s_waitcnt vmcnt(0) lgkmcnt(0)" ::: "memory");
    __builtin_amdgcn_s_barrier();
  };

  for (int t2 = 0; t2 < 32; ++t2) {
    body(0, 2 * t2);
    body(1, 2 * t2 + 1);
  }

  // ---- epilogue: KVU = bf16(u * pv) ----
  #pragma unroll
  for (int fm = 0; fm < 2; ++fm)
    #pragma unroll
    for (int fe = 0; fe < 4; ++fe)
      #pragma unroll
      for (int reg = 0; reg < 4; ++reg) {
        int ml = fm * 16 + kq * 4 + reg;
        size_t grow = (size_t)b * N_ + m0 + wm * 32 + ml;
        size_t ge = e0 + wl * 64 + fe * 16 + r16;
        float uu = b2f(U[grow * E_ + ge]);
        KVU[grow * E_ + ge] = f2b(uu * pv[fm][fe][reg]);
      }
}

extern "C" void kernel_launch(void* const* d_in, const int* in_sizes, int n_in,
                              void* d_out, int out_size, void* d_ws, size_t ws_size,
                              hipStream_t stream) {
  const float* query = (const float*)d_in[0];
  const float* ln_w  = (const float*)d_in[1];
  const float* ln_b  = (const float*)d_in[2];
  const float* Wu    = (const float*)d_in[3];
  const float* bu    = (const float*)d_in[4];
  const float* Wv    = (const float*)d_in[5];
  const float* bv    = (const float*)d_in[6];
  const float* Wbase = (const float*)d_in[7];
  const float* bbase = (const float*)d_in[8];
  const float* q_w   = (const float*)d_in[9];
  const float* q_b   = (const float*)d_in[10];
  const float* k_w   = (const float*)d_in[11];
  const float* k_b   = (const float*)d_in[12];
  const float* w_rel = (const float*)d_in[13];
  const float* Wo    = (const float*)d_in[14];
  const float* bo    = (const float*)d_in[15];
  float* out = (float*)d_out;

  char* ws = (char*)d_ws;
  ushort* X    = (ushort*)(ws);                     // 8192*256  (4 MB)
  ushort* U    = (ushort*)(ws + (4u  << 20));       // 8192*512  (8 MB)
  ushort* VT   = (ushort*)(ws + (12u << 20));       // 512*8192  (8 MB)
  ushort* BASE = (ushort*)(ws + (20u << 20));       // 8192*128  (2 MB)
  ushort* Qb   = (ushort*)(ws + (22u << 20));       // 2 MB
  ushort* Kb   = (ushort*)(ws + (24u << 20));       // 2 MB
  ushort* KVU  = (ushort*)(ws + (26u << 20));       // 8 MB
  ushort* WUT  = (ushort*)(ws + (34u << 20));
  ushort* WVT  = (ushort*)(ws + (34u << 20) + 512*256*2);
  ushort* WBT  = (ushort*)(ws + (34u << 20) + 2*512*256*2);
  ushort* WOT  = (ushort*)(ws + (34u << 20) + 2*512*256*2 + 128*256*2);

  ln_kernel<<<2048, 256, 0, stream>>>(query, ln_w, ln_b, X);
  wt_kernel<<<(512*256 + 255) / 256, 256, 0, stream>>>(Wu, WUT, 256, 512);
  wt_kernel<<<(512*256 + 255) / 256, 256, 0, stream>>>(Wv, WVT, 256, 512);
  wt_kernel<<<(128*256 + 255) / 256, 256, 0, stream>>>(Wbase, WBT, 256, 128);
  wt_kernel<<<(512*256 + 255) / 256, 256, 0, stream>>>(Wo, WOT, 512, 256);
  gemm_kernel<0><<<dim3(64, 8), 256, 0, stream>>>(X, WUT, bu, U, 8192, 512, 256);
  gemm_kernel<2><<<dim3(64, 8), 256, 0, stream>>>(X, WVT, bv, VT, 8192, 512, 256);
  gemm_kernel<0><<<dim3(64, 2), 256, 0, stream>>>(X, WBT, bbase, BASE, 8192, 128, 256);
  rope_kernel<<<2048, 256, 0, stream>>>(BASE, q_w, q_b, k_w, k_b, Qb, Kb);
  attn_kernel<<<dim3(64, 4, 2), 256, 0, stream>>>(Qb, Kb, VT, U, w_rel, KVU);
  gemm_kernel<1><<<dim3(64, 4), 256, 0, stream>>>(KVU, WOT, bo, out, 8192, 256, 512);
}